// Round 17
// baseline (69.717 us; speedup 1.0000x reference)
//
#include <hip/hip_runtime.h>
#include <hip/hip_bf16.h>

typedef unsigned short u16;
typedef unsigned int uint;
typedef __bf16 bf16x8 __attribute__((ext_vector_type(8)));
typedef float f32x16 __attribute__((ext_vector_type(16)));

#define SEQ 2048
#define DH  64
// ws: qT [32][2048][64] bf16 | kT [32][2048][64] bf16 | v [32][64][2048] bf16

__device__ __forceinline__ u16 f2bf(float x) {
  __bf16 h = (__bf16)x;
  return __builtin_bit_cast(u16, h);
}

// LDS chunk swizzle (16B chunks, 8 per 64-elem row): slot = ch ^ FSW(row).
// Uses row bits 0-2 only -> invariant under +8/+32 row offsets.
#define FSW(r) ((((r) & 3) << 1) | (((r) >> 2) & 1))

// ---- pre-pass 1: transpose q,k -> [bh][t][c] bf16 (q scaled by log2e/8) ----
__global__ __launch_bounds__(256) void transpose_qk(const float* __restrict__ qkv,
                                                    u16* __restrict__ qT,
                                                    u16* __restrict__ kT) {
  int idx = blockIdx.x;            // which(2) x bh(32) x ttile(32)
  int which = idx >> 10;
  int bh = (idx >> 5) & 31;
  int t0 = (idx & 31) * 64;
  int b = bh >> 3, h = bh & 7;
  const float* src = qkv + ((size_t)(b*1536 + which*512 + h*64)) * SEQ;
  u16* dst = (which ? kT : qT) + (size_t)bh * SEQ * DH;
  float scale = which ? 1.0f : 0.1803368801111244f;   // 0.125 * log2(e)

  __shared__ float tile[64][65];
  int tl = threadIdx.x & 63;
  int cw = threadIdx.x >> 6;
#pragma unroll
  for (int i = 0; i < 16; ++i) {
    int c = cw + 4*i;
    tile[c][tl] = src[(size_t)c*SEQ + t0 + tl] * scale;
  }
  __syncthreads();
  int cl2 = (threadIdx.x & 31) * 2;
  int tw  = threadIdx.x >> 5;
#pragma unroll
  for (int i = 0; i < 8; ++i) {
    int t = tw + 8*i;
    unsigned int lo = f2bf(tile[cl2][t]);
    unsigned int hi = f2bf(tile[cl2+1][t]);
    *(unsigned int*)(dst + (size_t)(t0 + t)*DH + cl2) = lo | (hi << 16);
  }
}

// ---- pre-pass 2: v -> bf16, native [bh][c][s] layout ----
__global__ __launch_bounds__(256) void convert_v(const float* __restrict__ qkv,
                                                 u16* __restrict__ v) {
  int row = blockIdx.x;            // bh*64 + c
  int bh = row >> 6, c = row & 63;
  int b = bh >> 3, h = bh & 7;
  const float4* src = (const float4*)(qkv + ((size_t)(b*1536 + 1024 + h*64 + c)) * SEQ);
  u16* dst = v + (size_t)row * SEQ;
  int tid = threadIdx.x;
  float4 a = src[tid*2];
  float4 bq = src[tid*2+1];
  union { u16 u[8]; int4 v4; } pk;
  pk.u[0]=f2bf(a.x); pk.u[1]=f2bf(a.y); pk.u[2]=f2bf(a.z); pk.u[3]=f2bf(a.w);
  pk.u[4]=f2bf(bq.x); pk.u[5]=f2bf(bq.y); pk.u[6]=f2bf(bq.z); pk.u[7]=f2bf(bq.w);
  *(int4*)(dst + tid*8) = pk.v4;
}

// ---- flash attention: T15 two-tile pipeline (QK(i+1) overlaps softmax(i)) ----
// r16 post-mortem: counted vmcnt = -5.5us (occupancy 4->2 blk/CU bundled).
// Plateau diagnosis: MfmaUtil 25% + VALUBusy 40%, neither saturated -> the
// per-tile serial chain ds_read->QK->exp2->pack->PV is the limit. Fix: hoist
// QK one tile ahead (T15): QK(i+1) [MFMA] is independent of softmax(i) [VALU]
// -> compiler interleaves; both pipes fed within a wave.
// 3-buffer LDS rotation (48KB, 3 blocks/CU): at tile i live bufs = V(i),
// K(i+1); free slot takes stage(i+2). Plain __syncthreads per tile (validated
// r14 form; drains same-iter stage, hidden under ~400cy compute).
// All else r14-verbatim: wave=(th 32 t-cols, sh s-half), fixed-m softmax
// (r9/r12), IN-LOOP l shfl (deferred form BANNED r10/r11), cross-sh epilogue.
__global__ __launch_bounds__(256, 3) void attn(const u16* __restrict__ qT,
                                               const u16* __restrict__ kT,
                                               const u16* __restrict__ vB,
                                               float* __restrict__ out) {
  // XCD-bijective swizzle (1024 blocks): 128 consecutive per XCD -> 4 heads/XCD
  const int lb = (blockIdx.x & 7) * 128 + (blockIdx.x >> 3);
  const int bh = lb >> 5;           // 32 t-tiles (of 64) per head
  const int t0 = (lb & 31) * 64;
  const int tid  = threadIdx.x;
  const int wave = tid >> 6;        // 0..3
  const int th   = wave & 1;        // t-half: cols t0 + th*32 + l31
  const int sh   = wave >> 1;       // s-half: rows sh*32 + l31 of each 64-tile
  const int lane = tid & 63;
  const int l31  = lane & 31;
  const int hi   = lane >> 5;

  // [buf 0..2][K=0/V=1][64 rows x 8 chunks of 16B] = 48KB
  __shared__ __align__(16) u16 smem[3][2][64*64];

  // Q B-frags: n=t=l31, k=8hi+j, c = kb*16+8hi+j
  const u16* qrow = qT + ((size_t)bh*SEQ + (t0 + th*32 + l31)) * DH;
  bf16x8 bq[4];
#pragma unroll
  for (int kb = 0; kb < 4; ++kb) bq[kb] = *(const bf16x8*)(qrow + kb*16 + hi*8);

  // staging: per thread 2 K-chunks + 2 V-chunks per 64-tile, pre-swizzled src
  const u16* ksrc0 = kT + (size_t)bh*SEQ*DH;
  const u16* vsrc0 = vB + (size_t)bh*DH*SEQ;
  const int ci0 = (wave*2+0)*64 + lane;   // chunk 0..511
  const int ci1 = (wave*2+1)*64 + lane;
  const int kr0 = ci0 >> 3, kc0 = ci0 & 7;
  const int kr1 = ci1 >> 3, kc1 = ci1 & 7;
  const u16* kg0 = ksrc0 + (size_t)kr0*DH + ((kc0 ^ FSW(kr0)) * 8);
  const u16* kg1 = ksrc0 + (size_t)kr1*DH + ((kc1 ^ FSW(kr1)) * 8);
  const u16* vg0 = vsrc0 + (size_t)kr0*SEQ + ((kc0 ^ FSW(kr0)) * 8);
  const u16* vg1 = vsrc0 + (size_t)kr1*SEQ + ((kc1 ^ FSW(kr1)) * 8);

#define GLDS(src, dst) __builtin_amdgcn_global_load_lds(                        \
    (const __attribute__((address_space(1))) unsigned int*)(src),               \
    (__attribute__((address_space(3))) unsigned int*)(dst), 16, 0, 0)
#define STAGE(b, sbase) do {                                                    \
    GLDS(kg0 + (size_t)(sbase)*DH, &smem[b][0][ci0*8]);                         \
    GLDS(kg1 + (size_t)(sbase)*DH, &smem[b][0][ci1*8]);                         \
    GLDS(vg0 + (sbase),            &smem[b][1][ci0*8]);                         \
    GLDS(vg1 + (sbase),            &smem[b][1][ci1*8]);                         \
  } while (0)

  // acc[cb]: D-partial[c=cb*32+crow(r,hi)][t=t0+th*32+l31], s in sh-half
  f32x16 acc0 = {}, acc1 = {};
  float l_run = 0.f;
  const int fl = FSW(l31);

  // QK for one tile (A rows = this wave's sh-half)
  auto QK = [&](const u16* kb_) -> f32x16 {
    f32x16 S = {};
    __builtin_amdgcn_s_setprio(1);
#pragma unroll
    for (int kb = 0; kb < 4; ++kb) {
      bf16x8 a = *(const bf16x8*)(kb_ + (sh*32 + l31)*64 + (((2*kb+hi) ^ fl) * 8));
      S = __builtin_amdgcn_mfma_f32_32x32x16_bf16(a, bq[kb], S, 0, 0, 0);
    }
    __builtin_amdgcn_s_setprio(0);
    return S;
  };

  // softmax + pack + PV for one tile
  auto SPV = [&](const f32x16& S0, const u16* vb_) {
    float p0[16];
#pragma unroll
    for (int i = 0; i < 16; ++i) p0[i] = __builtin_amdgcn_exp2f(S0[i]);
    {
      float sm[8];
#pragma unroll
      for (int i = 0; i < 8; ++i) sm[i] = p0[i] + p0[i+8];
#pragma unroll
      for (int i = 0; i < 4; ++i) sm[i] += sm[i+4];
      float ls = (sm[0] + sm[1]) + (sm[2] + sm[3]);
      ls += __shfl_xor(ls, 32);
      l_run += ls;
    }
    uint d0[8];
#pragma unroll
    for (int q = 0; q < 4; ++q)
#pragma unroll
      for (int e = 0; e < 2; ++e) {
        asm("v_cvt_pk_bf16_f32 %0, %1, %2" : "=v"(d0[2*q+e]) : "v"(p0[4*q+2*e]), "v"(p0[4*q+2*e+1]));
      }
    bf16x8 pf[2];
#pragma unroll
    for (int kb2 = 0; kb2 < 2; ++kb2) {
      uint X0 = d0[4*kb2+0], X1 = d0[4*kb2+1];
      uint Y0 = d0[4*kb2+2], Y1 = d0[4*kb2+3];
      asm("v_permlane32_swap_b32 %0, %1" : "+v"(X0), "+v"(Y0));
      asm("v_permlane32_swap_b32 %0, %1" : "+v"(X1), "+v"(Y1));
      uint4 u = {X0, X1, Y0, Y1};
      pf[kb2] = __builtin_bit_cast(bf16x8, u);
    }
    __builtin_amdgcn_s_setprio(1);
#pragma unroll
    for (int ks2 = 0; ks2 < 2; ++ks2) {
      bf16x8 av0 = *(const bf16x8*)(vb_ + l31*64      + (((sh*4 + ks2*2 + hi) ^ fl) * 8));
      bf16x8 av1 = *(const bf16x8*)(vb_ + (32+l31)*64 + (((sh*4 + ks2*2 + hi) ^ fl) * 8));
      acc0 = __builtin_amdgcn_mfma_f32_32x32x16_bf16(av0, pf[ks2], acc0, 0, 0, 0);
      acc1 = __builtin_amdgcn_mfma_f32_32x32x16_bf16(av1, pf[ks2], acc1, 0, 0, 0);
    }
    __builtin_amdgcn_s_setprio(0);
  };

  // prologue: stage tiles 0,1; drain; S(0)
  STAGE(0, 0);
  STAGE(1, 64);
  __syncthreads();
  f32x16 Sp = QK(&smem[0][0][0]);

  // main: iter i handles softmax/PV(i) while QK(i+1) runs; stage(i+2) -> free buf
  int cur = 0;
  for (int i = 0; i < 31; ++i) {
    int nxt = cur + 1; if (nxt == 3) nxt = 0;
    int stg = nxt + 1; if (stg == 3) stg = 0;
    if (i < 30) STAGE(stg, (i + 2) * 64);
    f32x16 Sn = QK(&smem[nxt][0][0]);   // MFMA, independent of SPV below
    SPV(Sp, &smem[cur][1][0]);          // VALU softmax + PV MFMA
    __syncthreads();                    // drains stage(i+2); syncs buf rotation
    Sp = Sn;
    cur = nxt;
  }
  SPV(Sp, &smem[cur][1][0]);            // tile 31
#undef STAGE
#undef GLDS

  __syncthreads();   // all waves done reading smem; safe to reuse for reduce

  // epilogue: reduce partials across sh via LDS (r14-validated layout).
  // [frag][r][lane]: bank = lane%32, 2-way (free). frag = th*2 + cb.
  float* ep = (float*)&smem[0][0][0];
  float* lp = ep + 4*1024;
  if (sh == 1) {
    float* b0 = ep + (th*2+0)*1024 + lane;
    float* b1 = ep + (th*2+1)*1024 + lane;
#pragma unroll
    for (int r = 0; r < 16; ++r) { b0[r*64] = acc0[r]; b1[r*64] = acc1[r]; }
    lp[th*64 + lane] = l_run;
  }
  __syncthreads();
  if (sh == 0) {
    const float* b0 = ep + (th*2+0)*1024 + lane;
    const float* b1 = ep + (th*2+1)*1024 + lane;
#pragma unroll
    for (int r = 0; r < 16; ++r) { acc0[r] += b0[r*64]; acc1[r] += b1[r*64]; }
    float lt = l_run + lp[th*64 + lane];
    float linv = 1.0f / lt;
    float* ob = out + (size_t)(bh*64) * SEQ + t0 + th*32 + l31;
#pragma unroll
    for (int r = 0; r < 16; ++r) {
      int c0 = (r & 3) + 8*(r >> 2) + 4*hi;
      ob[(size_t)c0 * SEQ]        = acc0[r] * linv;
      ob[(size_t)(32 + c0) * SEQ] = acc1[r] * linv;
    }
  }
}

extern "C" void kernel_launch(void* const* d_in, const int* in_sizes, int n_in,
                              void* d_out, int out_size, void* d_ws, size_t ws_size,
                              hipStream_t stream) {
  const float* qkv = (const float*)d_in[0];
  float* out = (float*)d_out;
  u16* qT = (u16*)d_ws;
  u16* kT = qT + (size_t)32*SEQ*DH;
  u16* vB = kT + (size_t)32*SEQ*DH;
  transpose_qk<<<2048, 256, 0, stream>>>(qkv, qT, kT);
  convert_v<<<2048, 256, 0, stream>>>(qkv, vB);
  attn<<<1024, 256, 0, stream>>>(qT, kT, vB, out);
}

// Round 18
// 65.811 us; speedup vs baseline: 1.0594x; 1.0594x over previous
//
#include <hip/hip_runtime.h>
#include <hip/hip_bf16.h>

typedef unsigned short u16;
typedef unsigned int uint;
typedef __bf16 bf16x8 __attribute__((ext_vector_type(8)));
typedef float f32x16 __attribute__((ext_vector_type(16)));

#define SEQ 2048
#define DH  64
// ws: qT [32][2048][64] bf16 | kT [32][2048][64] bf16 | v [32][64][2048] bf16

__device__ __forceinline__ u16 f2bf(float x) {
  __bf16 h = (__bf16)x;
  return __builtin_bit_cast(u16, h);
}

// LDS chunk swizzle (16B chunks, 8 per 64-elem row): slot = ch ^ FSW(row).
// Uses row bits 0-2 only -> invariant under +8/+32 row offsets.
#define FSW(r) ((((r) & 3) << 1) | (((r) >> 2) & 1))

// ---- pre-pass 1: transpose q,k -> [bh][t][c] bf16 (q scaled by log2e/8) ----
__global__ __launch_bounds__(256) void transpose_qk(const float* __restrict__ qkv,
                                                    u16* __restrict__ qT,
                                                    u16* __restrict__ kT) {
  int idx = blockIdx.x;            // which(2) x bh(32) x ttile(32)
  int which = idx >> 10;
  int bh = (idx >> 5) & 31;
  int t0 = (idx & 31) * 64;
  int b = bh >> 3, h = bh & 7;
  const float* src = qkv + ((size_t)(b*1536 + which*512 + h*64)) * SEQ;
  u16* dst = (which ? kT : qT) + (size_t)bh * SEQ * DH;
  float scale = which ? 1.0f : 0.1803368801111244f;   // 0.125 * log2(e)

  __shared__ float tile[64][65];
  int tl = threadIdx.x & 63;
  int cw = threadIdx.x >> 6;
#pragma unroll
  for (int i = 0; i < 16; ++i) {
    int c = cw + 4*i;
    tile[c][tl] = src[(size_t)c*SEQ + t0 + tl] * scale;
  }
  __syncthreads();
  int cl2 = (threadIdx.x & 31) * 2;
  int tw  = threadIdx.x >> 5;
#pragma unroll
  for (int i = 0; i < 8; ++i) {
    int t = tw + 8*i;
    unsigned int lo = f2bf(tile[cl2][t]);
    unsigned int hi = f2bf(tile[cl2+1][t]);
    *(unsigned int*)(dst + (size_t)(t0 + t)*DH + cl2) = lo | (hi << 16);
  }
}

// ---- pre-pass 2: v -> bf16, native [bh][c][s] layout ----
__global__ __launch_bounds__(256) void convert_v(const float* __restrict__ qkv,
                                                 u16* __restrict__ v) {
  int row = blockIdx.x;            // bh*64 + c
  int bh = row >> 6, c = row & 63;
  int b = bh >> 3, h = bh & 7;
  const float4* src = (const float4*)(qkv + ((size_t)(b*1536 + 1024 + h*64 + c)) * SEQ);
  u16* dst = v + (size_t)row * SEQ;
  int tid = threadIdx.x;
  float4 a = src[tid*2];
  float4 bq = src[tid*2+1];
  union { u16 u[8]; int4 v4; } pk;
  pk.u[0]=f2bf(a.x); pk.u[1]=f2bf(a.y); pk.u[2]=f2bf(a.z); pk.u[3]=f2bf(a.w);
  pk.u[4]=f2bf(bq.x); pk.u[5]=f2bf(bq.y); pk.u[6]=f2bf(bq.z); pk.u[7]=f2bf(bq.w);
  *(int4*)(dst + tid*8) = pk.v4;
}

// ---- flash attention: r14 geometry + l-via-MFMA (ones A-fragment) ----
// r17 post-mortem: T15 pipeline -6us; 6 structural probes flat -> schedule
// plateau. Remaining excess = VALU (41% busy: exp2 quarter-rate + tree + shfl)
// while MFMA pipe ~6% busy. Move l-reduction to MFMA: lacc = mfma(ones, pf)
// gives lacc[r][t] = sum_s P[s][t] over the wave's full 32-row sh-half (k-dim
// spans hi) -> deletes the sum tree AND the in-loop ds_bpermute shfl entirely
// (no cross-lane l op outside MFMA; distinct from the BANNED deferred-shfl).
// l = sum of bf16-rounded p, consistent with the PV numerator.
// All else r14-verbatim: 1024 blocks x 4 waves (th 32 t-cols, sh s-half),
// BK=64, 32KB dbuf LDS, 4 blocks/CU, fixed-m softmax, cross-sh epilogue.
__global__ __launch_bounds__(256, 4) void attn(const u16* __restrict__ qT,
                                               const u16* __restrict__ kT,
                                               const u16* __restrict__ vB,
                                               float* __restrict__ out) {
  // XCD-bijective swizzle (1024 blocks): 128 consecutive per XCD -> 4 heads/XCD
  const int lb = (blockIdx.x & 7) * 128 + (blockIdx.x >> 3);
  const int bh = lb >> 5;           // 32 t-tiles (of 64) per head
  const int t0 = (lb & 31) * 64;
  const int tid  = threadIdx.x;
  const int wave = tid >> 6;        // 0..3
  const int th   = wave & 1;        // t-half: cols t0 + th*32 + l31
  const int sh   = wave >> 1;       // s-half: rows sh*32 + l31 of each 64-tile
  const int lane = tid & 63;
  const int l31  = lane & 31;
  const int hi   = lane >> 5;

  // [buf][K=0/V=1][64 rows x 8 chunks of 16B] = 32KB
  __shared__ __align__(16) u16 smem[2][2][64*64];

  // Q B-frags: n=t=l31, k=8hi+j, c = kb*16+8hi+j
  const u16* qrow = qT + ((size_t)bh*SEQ + (t0 + th*32 + l31)) * DH;
  bf16x8 bq[4];
#pragma unroll
  for (int kb = 0; kb < 4; ++kb) bq[kb] = *(const bf16x8*)(qrow + kb*16 + hi*8);

  // ones A-fragment (bf16 1.0 = 0x3F80) for the l-MFMA
  const uint4 uones = {0x3F803F80u, 0x3F803F80u, 0x3F803F80u, 0x3F803F80u};
  const bf16x8 aone = __builtin_bit_cast(bf16x8, uones);

  // staging: per thread 2 K-chunks + 2 V-chunks per 64-tile, pre-swizzled src
  const u16* ksrc0 = kT + (size_t)bh*SEQ*DH;
  const u16* vsrc0 = vB + (size_t)bh*DH*SEQ;
  const int ci0 = (wave*2+0)*64 + lane;   // chunk 0..511
  const int ci1 = (wave*2+1)*64 + lane;
  const int kr0 = ci0 >> 3, kc0 = ci0 & 7;
  const int kr1 = ci1 >> 3, kc1 = ci1 & 7;
  const u16* kg0 = ksrc0 + (size_t)kr0*DH + ((kc0 ^ FSW(kr0)) * 8);
  const u16* kg1 = ksrc0 + (size_t)kr1*DH + ((kc1 ^ FSW(kr1)) * 8);
  const u16* vg0 = vsrc0 + (size_t)kr0*SEQ + ((kc0 ^ FSW(kr0)) * 8);
  const u16* vg1 = vsrc0 + (size_t)kr1*SEQ + ((kc1 ^ FSW(kr1)) * 8);

#define GLDS(src, dst) __builtin_amdgcn_global_load_lds(                        \
    (const __attribute__((address_space(1))) unsigned int*)(src),               \
    (__attribute__((address_space(3))) unsigned int*)(dst), 16, 0, 0)
#define STAGE(b, sbase) do {                                                    \
    GLDS(kg0 + (size_t)(sbase)*DH, &smem[b][0][ci0*8]);                         \
    GLDS(kg1 + (size_t)(sbase)*DH, &smem[b][0][ci1*8]);                         \
    GLDS(vg0 + (sbase),            &smem[b][1][ci0*8]);                         \
    GLDS(vg1 + (sbase),            &smem[b][1][ci1*8]);                         \
  } while (0)

  // acc[cb]: D-partial[c=cb*32+crow(r,hi)][t=t0+th*32+l31], s in sh-half
  // lacc: l-partial (all 16 entries identical = sum_s P over sh-half)
  f32x16 acc0 = {}, acc1 = {}, lacc = {};
  const int fl = FSW(l31);

  STAGE(0, 0);
  __syncthreads();

  int buf = 0;
  for (int s0 = 0; s0 < SEQ; s0 += 64) {
    if (s0 + 64 < SEQ) STAGE(buf ^ 1, s0 + 64);

    const u16* kb_ = &smem[buf][0][0];
    const u16* vb_ = &smem[buf][1][0];

    // QK^T swapped: S^T = K*Q; A rows = sh*32+l31 (this wave's s-half only)
    f32x16 S0 = {};
    __builtin_amdgcn_s_setprio(1);
#pragma unroll
    for (int kb = 0; kb < 4; ++kb) {
      bf16x8 a = *(const bf16x8*)(kb_ + (sh*32 + l31)*64 + (((2*kb+hi) ^ fl) * 8));
      S0 = __builtin_amdgcn_mfma_f32_32x32x16_bf16(a, bq[kb], S0, 0, 0, 0);
    }
    __builtin_amdgcn_s_setprio(0);

    // fixed-m softmax: P = exp2(S) -> bf16 pack (no tree, no shfl: l via MFMA)
    float p0[16];
#pragma unroll
    for (int i = 0; i < 16; ++i) p0[i] = __builtin_amdgcn_exp2f(S0[i]);

    // pack P: d0[2q+e] = (p[4q+2e], p[4q+2e+1]) -> s-local = 8q+4hi+2e(+1)
    uint d0[8];
#pragma unroll
    for (int q = 0; q < 4; ++q)
#pragma unroll
      for (int e = 0; e < 2; ++e) {
        asm("v_cvt_pk_bf16_f32 %0, %1, %2" : "=v"(d0[2*q+e]) : "v"(p0[4*q+2*e]), "v"(p0[4*q+2*e+1]));
      }
    // swap(D=X, S=Y): X' = pf dword0/1, Y' = pf dword2/3 (distinct values)
    bf16x8 pf[2];   // [ks2]: k = s-local 16ks2..+15
#pragma unroll
    for (int kb2 = 0; kb2 < 2; ++kb2) {
      uint X0 = d0[4*kb2+0], X1 = d0[4*kb2+1];
      uint Y0 = d0[4*kb2+2], Y1 = d0[4*kb2+3];
      asm("v_permlane32_swap_b32 %0, %1" : "+v"(X0), "+v"(Y0));
      asm("v_permlane32_swap_b32 %0, %1" : "+v"(X1), "+v"(Y1));
      uint4 u = {X0, X1, Y0, Y1};
      pf[kb2] = __builtin_bit_cast(bf16x8, u);
    }

    // PV partial + l-MFMA: V A-frag rows cb*32+l31, s-cols of this sh-half
    __builtin_amdgcn_s_setprio(1);
#pragma unroll
    for (int ks2 = 0; ks2 < 2; ++ks2) {
      bf16x8 av0 = *(const bf16x8*)(vb_ + l31*64      + (((sh*4 + ks2*2 + hi) ^ fl) * 8));
      bf16x8 av1 = *(const bf16x8*)(vb_ + (32+l31)*64 + (((sh*4 + ks2*2 + hi) ^ fl) * 8));
      acc0 = __builtin_amdgcn_mfma_f32_32x32x16_bf16(av0, pf[ks2], acc0, 0, 0, 0);
      acc1 = __builtin_amdgcn_mfma_f32_32x32x16_bf16(av1, pf[ks2], acc1, 0, 0, 0);
      lacc = __builtin_amdgcn_mfma_f32_32x32x16_bf16(aone, pf[ks2], lacc, 0, 0, 0);
    }
    __builtin_amdgcn_s_setprio(0);

    __syncthreads();   // all waves done with buf; prefetch into buf^1 landed
    buf ^= 1;
  }
#undef STAGE
#undef GLDS

  // epilogue: reduce partials across sh via LDS (r14-validated layout).
  // [frag][r][lane]: bank = lane%32, 2-way (free). frag = th*2 + cb.
  // l: lacc[0] (all entries equal; k-dim already summed both hi halves).
  float* ep = (float*)&smem[0][0][0];
  float* lp = ep + 4*1024;
  if (sh == 1) {
    float* b0 = ep + (th*2+0)*1024 + lane;
    float* b1 = ep + (th*2+1)*1024 + lane;
#pragma unroll
    for (int r = 0; r < 16; ++r) { b0[r*64] = acc0[r]; b1[r*64] = acc1[r]; }
    lp[th*64 + lane] = lacc[0];
  }
  __syncthreads();
  if (sh == 0) {
    const float* b0 = ep + (th*2+0)*1024 + lane;
    const float* b1 = ep + (th*2+1)*1024 + lane;
#pragma unroll
    for (int r = 0; r < 16; ++r) { acc0[r] += b0[r*64]; acc1[r] += b1[r*64]; }
    float lt = lacc[0] + lp[th*64 + lane];
    float linv = 1.0f / lt;
    float* ob = out + (size_t)(bh*64) * SEQ + t0 + th*32 + l31;
#pragma unroll
    for (int r = 0; r < 16; ++r) {
      int c0 = (r & 3) + 8*(r >> 2) + 4*hi;
      ob[(size_t)c0 * SEQ]        = acc0[r] * linv;
      ob[(size_t)(32 + c0) * SEQ] = acc1[r] * linv;
    }
  }
}

extern "C" void kernel_launch(void* const* d_in, const int* in_sizes, int n_in,
                              void* d_out, int out_size, void* d_ws, size_t ws_size,
                              hipStream_t stream) {
  const float* qkv = (const float*)d_in[0];
  float* out = (float*)d_out;
  u16* qT = (u16*)d_ws;
  u16* kT = qT + (size_t)32*SEQ*DH;
  u16* vB = kT + (size_t)32*SEQ*DH;
  transpose_qk<<<2048, 256, 0, stream>>>(qkv, qT, kT);
  convert_v<<<2048, 256, 0, stream>>>(qkv, vB);
  attn<<<1024, 256, 0, stream>>>(qT, kT, vB, out);
}

// Round 19
// 63.663 us; speedup vs baseline: 1.0951x; 1.0337x over previous
//
#include <hip/hip_runtime.h>
#include <hip/hip_bf16.h>

typedef unsigned short u16;
typedef unsigned int uint;
typedef __bf16 bf16x8 __attribute__((ext_vector_type(8)));
typedef float f32x16 __attribute__((ext_vector_type(16)));

#define SEQ 2048
#define DH  64
// ws: qT [32][2048][64] bf16 | kT [32][2048][64] bf16 | v [32][64][2048] bf16

__device__ __forceinline__ u16 f2bf(float x) {
  __bf16 h = (__bf16)x;
  return __builtin_bit_cast(u16, h);
}

// LDS chunk swizzle (16B chunks, 8 per 64-elem row): slot = ch ^ FSW(row).
// Uses row bits 0-2 only -> invariant under +8/+32 row offsets.
#define FSW(r) ((((r) & 3) << 1) | (((r) >> 2) & 1))

// ---- fused pre-pass (single launch, 4096 blocks):
// blocks 0..2047: q,k -> [bh][t][c] bf16 (q scaled by log2e/8)
// blocks 2048..4095: v -> bf16 [bh][c][s]
// (fusion exonerated by r11/r12 bisect: r10's failure was the attn change)
__global__ __launch_bounds__(256) void prepass(const float* __restrict__ qkv,
                                               u16* __restrict__ qT,
                                               u16* __restrict__ kT,
                                               u16* __restrict__ vB) {
  int idx = blockIdx.x;
  __shared__ float tile[64][65];
  if (idx < 2048) {
    // transpose q/k: idx = which(2) x bh(32) x ttile(32)
    int which = idx >> 10;
    int bh = (idx >> 5) & 31;
    int t0 = (idx & 31) * 64;
    int b = bh >> 3, h = bh & 7;
    const float* src = qkv + ((size_t)(b*1536 + which*512 + h*64)) * SEQ;
    u16* dst = (which ? kT : qT) + (size_t)bh * SEQ * DH;
    float scale = which ? 1.0f : 0.1803368801111244f;   // 0.125 * log2(e)

    int tl = threadIdx.x & 63;
    int cw = threadIdx.x >> 6;
#pragma unroll
    for (int i = 0; i < 16; ++i) {
      int c = cw + 4*i;
      tile[c][tl] = src[(size_t)c*SEQ + t0 + tl] * scale;
    }
    __syncthreads();
    int cl2 = (threadIdx.x & 31) * 2;
    int tw  = threadIdx.x >> 5;
#pragma unroll
    for (int i = 0; i < 8; ++i) {
      int t = tw + 8*i;
      unsigned int lo = f2bf(tile[cl2][t]);
      unsigned int hi = f2bf(tile[cl2+1][t]);
      *(unsigned int*)(dst + (size_t)(t0 + t)*DH + cl2) = lo | (hi << 16);
    }
  } else {
    // convert v row: row = idx - 2048 = bh*64 + c
    int row = idx - 2048;
    int bh = row >> 6, c = row & 63;
    int b = bh >> 3, h = bh & 7;
    const float4* src = (const float4*)(qkv + ((size_t)(b*1536 + 1024 + h*64 + c)) * SEQ);
    u16* dst = vB + (size_t)row * SEQ;
    int tid = threadIdx.x;
    float4 a = src[tid*2];
    float4 bq = src[tid*2+1];
    union { u16 u[8]; int4 v4; } pk;
    pk.u[0]=f2bf(a.x); pk.u[1]=f2bf(a.y); pk.u[2]=f2bf(a.z); pk.u[3]=f2bf(a.w);
    pk.u[4]=f2bf(bq.x); pk.u[5]=f2bf(bq.y); pk.u[6]=f2bf(bq.z); pk.u[7]=f2bf(bq.w);
    *(int4*)(dst + tid*8) = pk.v4;
  }
}

// ---- flash attention: r18 verbatim (best: 52.2us, MfmaUtil 35%) ----
// r14 geometry + l-via-MFMA (ones A-frag): lacc = mfma(ones, pf) sums P over
// the wave's full 32-row sh-half on the 35%-busy MFMA pipe; no in-loop
// cross-lane l op (distinct from BANNED deferred-shfl). Fixed-m softmax
// (m=0, r9/r12-validated). 1024 blocks x 4 waves (th 32 t-cols, sh s-half),
// BK=64, 32KB dbuf LDS, 4 blocks/CU, cross-sh epilogue LDS reduce.
__global__ __launch_bounds__(256, 4) void attn(const u16* __restrict__ qT,
                                               const u16* __restrict__ kT,
                                               const u16* __restrict__ vB,
                                               float* __restrict__ out) {
  // XCD-bijective swizzle (1024 blocks): 128 consecutive per XCD -> 4 heads/XCD
  const int lb = (blockIdx.x & 7) * 128 + (blockIdx.x >> 3);
  const int bh = lb >> 5;           // 32 t-tiles (of 64) per head
  const int t0 = (lb & 31) * 64;
  const int tid  = threadIdx.x;
  const int wave = tid >> 6;        // 0..3
  const int th   = wave & 1;        // t-half: cols t0 + th*32 + l31
  const int sh   = wave >> 1;       // s-half: rows sh*32 + l31 of each 64-tile
  const int lane = tid & 63;
  const int l31  = lane & 31;
  const int hi   = lane >> 5;

  // [buf][K=0/V=1][64 rows x 8 chunks of 16B] = 32KB
  __shared__ __align__(16) u16 smem[2][2][64*64];

  // Q B-frags: n=t=l31, k=8hi+j, c = kb*16+8hi+j
  const u16* qrow = qT + ((size_t)bh*SEQ + (t0 + th*32 + l31)) * DH;
  bf16x8 bq[4];
#pragma unroll
  for (int kb = 0; kb < 4; ++kb) bq[kb] = *(const bf16x8*)(qrow + kb*16 + hi*8);

  // ones A-fragment (bf16 1.0 = 0x3F80) for the l-MFMA
  const uint4 uones = {0x3F803F80u, 0x3F803F80u, 0x3F803F80u, 0x3F803F80u};
  const bf16x8 aone = __builtin_bit_cast(bf16x8, uones);

  // staging: per thread 2 K-chunks + 2 V-chunks per 64-tile, pre-swizzled src
  const u16* ksrc0 = kT + (size_t)bh*SEQ*DH;
  const u16* vsrc0 = vB + (size_t)bh*DH*SEQ;
  const int ci0 = (wave*2+0)*64 + lane;   // chunk 0..511
  const int ci1 = (wave*2+1)*64 + lane;
  const int kr0 = ci0 >> 3, kc0 = ci0 & 7;
  const int kr1 = ci1 >> 3, kc1 = ci1 & 7;
  const u16* kg0 = ksrc0 + (size_t)kr0*DH + ((kc0 ^ FSW(kr0)) * 8);
  const u16* kg1 = ksrc0 + (size_t)kr1*DH + ((kc1 ^ FSW(kr1)) * 8);
  const u16* vg0 = vsrc0 + (size_t)kr0*SEQ + ((kc0 ^ FSW(kr0)) * 8);
  const u16* vg1 = vsrc0 + (size_t)kr1*SEQ + ((kc1 ^ FSW(kr1)) * 8);

#define GLDS(src, dst) __builtin_amdgcn_global_load_lds(                        \
    (const __attribute__((address_space(1))) unsigned int*)(src),               \
    (__attribute__((address_space(3))) unsigned int*)(dst), 16, 0, 0)
#define STAGE(b, sbase) do {                                                    \
    GLDS(kg0 + (size_t)(sbase)*DH, &smem[b][0][ci0*8]);                         \
    GLDS(kg1 + (size_t)(sbase)*DH, &smem[b][0][ci1*8]);                         \
    GLDS(vg0 + (sbase),            &smem[b][1][ci0*8]);                         \
    GLDS(vg1 + (sbase),            &smem[b][1][ci1*8]);                         \
  } while (0)

  // acc[cb]: D-partial[c=cb*32+crow(r,hi)][t=t0+th*32+l31], s in sh-half
  // lacc: l-partial (all 16 entries identical = sum_s P over sh-half)
  f32x16 acc0 = {}, acc1 = {}, lacc = {};
  const int fl = FSW(l31);

  STAGE(0, 0);
  __syncthreads();

  int buf = 0;
  for (int s0 = 0; s0 < SEQ; s0 += 64) {
    if (s0 + 64 < SEQ) STAGE(buf ^ 1, s0 + 64);

    const u16* kb_ = &smem[buf][0][0];
    const u16* vb_ = &smem[buf][1][0];

    // QK^T swapped: S^T = K*Q; A rows = sh*32+l31 (this wave's s-half only)
    f32x16 S0 = {};
    __builtin_amdgcn_s_setprio(1);
#pragma unroll
    for (int kb = 0; kb < 4; ++kb) {
      bf16x8 a = *(const bf16x8*)(kb_ + (sh*32 + l31)*64 + (((2*kb+hi) ^ fl) * 8));
      S0 = __builtin_amdgcn_mfma_f32_32x32x16_bf16(a, bq[kb], S0, 0, 0, 0);
    }
    __builtin_amdgcn_s_setprio(0);

    // fixed-m softmax: P = exp2(S) -> bf16 pack (no tree, no shfl: l via MFMA)
    float p0[16];
#pragma unroll
    for (int i = 0; i < 16; ++i) p0[i] = __builtin_amdgcn_exp2f(S0[i]);

    // pack P: d0[2q+e] = (p[4q+2e], p[4q+2e+1]) -> s-local = 8q+4hi+2e(+1)
    uint d0[8];
#pragma unroll
    for (int q = 0; q < 4; ++q)
#pragma unroll
      for (int e = 0; e < 2; ++e) {
        asm("v_cvt_pk_bf16_f32 %0, %1, %2" : "=v"(d0[2*q+e]) : "v"(p0[4*q+2*e]), "v"(p0[4*q+2*e+1]));
      }
    // swap(D=X, S=Y): X' = pf dword0/1, Y' = pf dword2/3 (distinct values)
    bf16x8 pf[2];   // [ks2]: k = s-local 16ks2..+15
#pragma unroll
    for (int kb2 = 0; kb2 < 2; ++kb2) {
      uint X0 = d0[4*kb2+0], X1 = d0[4*kb2+1];
      uint Y0 = d0[4*kb2+2], Y1 = d0[4*kb2+3];
      asm("v_permlane32_swap_b32 %0, %1" : "+v"(X0), "+v"(Y0));
      asm("v_permlane32_swap_b32 %0, %1" : "+v"(X1), "+v"(Y1));
      uint4 u = {X0, X1, Y0, Y1};
      pf[kb2] = __builtin_bit_cast(bf16x8, u);
    }

    // PV partial + l-MFMA: V A-frag rows cb*32+l31, s-cols of this sh-half
    __builtin_amdgcn_s_setprio(1);
#pragma unroll
    for (int ks2 = 0; ks2 < 2; ++ks2) {
      bf16x8 av0 = *(const bf16x8*)(vb_ + l31*64      + (((sh*4 + ks2*2 + hi) ^ fl) * 8));
      bf16x8 av1 = *(const bf16x8*)(vb_ + (32+l31)*64 + (((sh*4 + ks2*2 + hi) ^ fl) * 8));
      acc0 = __builtin_amdgcn_mfma_f32_32x32x16_bf16(av0, pf[ks2], acc0, 0, 0, 0);
      acc1 = __builtin_amdgcn_mfma_f32_32x32x16_bf16(av1, pf[ks2], acc1, 0, 0, 0);
      lacc = __builtin_amdgcn_mfma_f32_32x32x16_bf16(aone, pf[ks2], lacc, 0, 0, 0);
    }
    __builtin_amdgcn_s_setprio(0);

    __syncthreads();   // all waves done with buf; prefetch into buf^1 landed
    buf ^= 1;
  }
#undef STAGE
#undef GLDS

  // epilogue: reduce partials across sh via LDS (r14-validated layout).
  // [frag][r][lane]: bank = lane%32, 2-way (free). frag = th*2 + cb.
  // l: lacc[0] (all entries equal; k-dim already summed both hi halves).
  float* ep = (float*)&smem[0][0][0];
  float* lp = ep + 4*1024;
  if (sh == 1) {
    float* b0 = ep + (th*2+0)*1024 + lane;
    float* b1 = ep + (th*2+1)*1024 + lane;
#pragma unroll
    for (int r = 0; r < 16; ++r) { b0[r*64] = acc0[r]; b1[r*64] = acc1[r]; }
    lp[th*64 + lane] = lacc[0];
  }
  __syncthreads();
  if (sh == 0) {
    const float* b0 = ep + (th*2+0)*1024 + lane;
    const float* b1 = ep + (th*2+1)*1024 + lane;
#pragma unroll
    for (int r = 0; r < 16; ++r) { acc0[r] += b0[r*64]; acc1[r] += b1[r*64]; }
    float lt = lacc[0] + lp[th*64 + lane];
    float linv = 1.0f / lt;
    float* ob = out + (size_t)(bh*64) * SEQ + t0 + th*32 + l31;
#pragma unroll
    for (int r = 0; r < 16; ++r) {
      int c0 = (r & 3) + 8*(r >> 2) + 4*hi;
      ob[(size_t)c0 * SEQ]        = acc0[r] * linv;
      ob[(size_t)(32 + c0) * SEQ] = acc1[r] * linv;
    }
  }
}

extern "C" void kernel_launch(void* const* d_in, const int* in_sizes, int n_in,
                              void* d_out, int out_size, void* d_ws, size_t ws_size,
                              hipStream_t stream) {
  const float* qkv = (const float*)d_in[0];
  float* out = (float*)d_out;
  u16* qT = (u16*)d_ws;
  u16* kT = qT + (size_t)32*SEQ*DH;
  u16* vB = kT + (size_t)32*SEQ*DH;
  prepass<<<4096, 256, 0, stream>>>(qkv, qT, kT, vB);
  attn<<<1024, 256, 0, stream>>>(qT, kT, vB, out);
}

// Round 20
// 62.604 us; speedup vs baseline: 1.1136x; 1.0169x over previous
//
#include <hip/hip_runtime.h>
#include <hip/hip_bf16.h>

typedef unsigned short u16;
typedef unsigned int uint;
typedef __bf16 bf16x8 __attribute__((ext_vector_type(8)));
typedef float f32x16 __attribute__((ext_vector_type(16)));

#define SEQ 2048
#define DH  64
// ws: qT [32][2048][64] bf16 | kT [32][2048][64] bf16 | v [32][64][2048] bf16

__device__ __forceinline__ u16 f2bf(float x) {
  __bf16 h = (__bf16)x;
  return __builtin_bit_cast(u16, h);
}

// LDS chunk swizzle (16B chunks, 8 per 64-elem row): slot = ch ^ FSW(row).
// Uses row bits 0-2 only -> invariant under +8/+32 row offsets.
#define FSW(r) ((((r) & 3) << 1) | (((r) >> 2) & 1))

// ---- fused pre-pass (single launch, 4096 blocks) ----
__global__ __launch_bounds__(256) void prepass(const float* __restrict__ qkv,
                                               u16* __restrict__ qT,
                                               u16* __restrict__ kT,
                                               u16* __restrict__ vB) {
  int idx = blockIdx.x;
  __shared__ float tile[64][65];
  if (idx < 2048) {
    // transpose q/k: idx = which(2) x bh(32) x ttile(32)
    int which = idx >> 10;
    int bh = (idx >> 5) & 31;
    int t0 = (idx & 31) * 64;
    int b = bh >> 3, h = bh & 7;
    const float* src = qkv + ((size_t)(b*1536 + which*512 + h*64)) * SEQ;
    u16* dst = (which ? kT : qT) + (size_t)bh * SEQ * DH;
    float scale = which ? 1.0f : 0.1803368801111244f;   // 0.125 * log2(e)

    int tl = threadIdx.x & 63;
    int cw = threadIdx.x >> 6;
#pragma unroll
    for (int i = 0; i < 16; ++i) {
      int c = cw + 4*i;
      tile[c][tl] = src[(size_t)c*SEQ + t0 + tl] * scale;
    }
    __syncthreads();
    int cl2 = (threadIdx.x & 31) * 2;
    int tw  = threadIdx.x >> 5;
#pragma unroll
    for (int i = 0; i < 8; ++i) {
      int t = tw + 8*i;
      unsigned int lo = f2bf(tile[cl2][t]);
      unsigned int hi = f2bf(tile[cl2+1][t]);
      *(unsigned int*)(dst + (size_t)(t0 + t)*DH + cl2) = lo | (hi << 16);
    }
  } else {
    // convert v row: row = idx - 2048 = bh*64 + c
    int row = idx - 2048;
    int bh = row >> 6, c = row & 63;
    int b = bh >> 3, h = bh & 7;
    const float4* src = (const float4*)(qkv + ((size_t)(b*1536 + 1024 + h*64 + c)) * SEQ);
    u16* dst = vB + (size_t)row * SEQ;
    int tid = threadIdx.x;
    float4 a = src[tid*2];
    float4 bq = src[tid*2+1];
    union { u16 u[8]; int4 v4; } pk;
    pk.u[0]=f2bf(a.x); pk.u[1]=f2bf(a.y); pk.u[2]=f2bf(a.z); pk.u[3]=f2bf(a.w);
    pk.u[4]=f2bf(bq.x); pk.u[5]=f2bf(bq.y); pk.u[6]=f2bf(bq.z); pk.u[7]=f2bf(bq.w);
    *(int4*)(dst + tid*8) = pk.v4;
  }
}

// ---- flash attention: r18 semantics + VALU/address trim ----
// Trim set (no layout/sync change): (1) all 8 LDS fragment pointers hoisted
// out of the loop; (2) s-loop unrolled x2 so buf is COMPILE-TIME -> buf*16KB
// folds into ds_read offset immediates (per-tile read-address VALU = 0);
// (3) first QK MFMA uses persistent fzero as C (no per-tile 16-reg zero-init).
// Carried validated: l-via-MFMA (ones A-frag), fixed-m softmax (m=0),
// 1024 blocks x 4 waves (th 32 t-cols, sh s-half), BK=64, 32KB dbuf LDS,
// 4 blocks/CU, cross-sh epilogue LDS reduce.
__global__ __launch_bounds__(256, 4) void attn(const u16* __restrict__ qT,
                                               const u16* __restrict__ kT,
                                               const u16* __restrict__ vB,
                                               float* __restrict__ out) {
  // XCD-bijective swizzle (1024 blocks): 128 consecutive per XCD -> 4 heads/XCD
  const int lb = (blockIdx.x & 7) * 128 + (blockIdx.x >> 3);
  const int bh = lb >> 5;           // 32 t-tiles (of 64) per head
  const int t0 = (lb & 31) * 64;
  const int tid  = threadIdx.x;
  const int wave = tid >> 6;        // 0..3
  const int th   = wave & 1;        // t-half: cols t0 + th*32 + l31
  const int sh   = wave >> 1;       // s-half: rows sh*32 + l31 of each 64-tile
  const int lane = tid & 63;
  const int l31  = lane & 31;
  const int hi   = lane >> 5;

  // [buf][K=0/V=1][64 rows x 8 chunks of 16B] = 32KB
  __shared__ __align__(16) u16 smem[2][2][64*64];

  // Q B-frags: n=t=l31, k=8hi+j, c = kb*16+8hi+j
  const u16* qrow = qT + ((size_t)bh*SEQ + (t0 + th*32 + l31)) * DH;
  bf16x8 bq[4];
#pragma unroll
  for (int kb = 0; kb < 4; ++kb) bq[kb] = *(const bf16x8*)(qrow + kb*16 + hi*8);

  // ones A-fragment (bf16 1.0 = 0x3F80) for the l-MFMA; persistent zero C
  const uint4 uones = {0x3F803F80u, 0x3F803F80u, 0x3F803F80u, 0x3F803F80u};
  const bf16x8 aone = __builtin_bit_cast(bf16x8, uones);
  const f32x16 fzero = {};

  // staging: per thread 2 K-chunks + 2 V-chunks per 64-tile, pre-swizzled src
  const u16* ksrc0 = kT + (size_t)bh*SEQ*DH;
  const u16* vsrc0 = vB + (size_t)bh*DH*SEQ;
  const int ci0 = (wave*2+0)*64 + lane;   // chunk 0..511
  const int ci1 = (wave*2+1)*64 + lane;
  const int kr0 = ci0 >> 3, kc0 = ci0 & 7;
  const int kr1 = ci1 >> 3, kc1 = ci1 & 7;
  const u16* kg0 = ksrc0 + (size_t)kr0*DH + ((kc0 ^ FSW(kr0)) * 8);
  const u16* kg1 = ksrc0 + (size_t)kr1*DH + ((kc1 ^ FSW(kr1)) * 8);
  const u16* vg0 = vsrc0 + (size_t)kr0*SEQ + ((kc0 ^ FSW(kr0)) * 8);
  const u16* vg1 = vsrc0 + (size_t)kr1*SEQ + ((kc1 ^ FSW(kr1)) * 8);

#define GLDS(src, dst) __builtin_amdgcn_global_load_lds(                        \
    (const __attribute__((address_space(1))) unsigned int*)(src),               \
    (__attribute__((address_space(3))) unsigned int*)(dst), 16, 0, 0)
#define STAGE(b, sbase) do {                                                    \
    GLDS(kg0 + (size_t)(sbase)*DH, &smem[b][0][ci0*8]);                         \
    GLDS(kg1 + (size_t)(sbase)*DH, &smem[b][0][ci1*8]);                         \
    GLDS(vg0 + (sbase),            &smem[b][1][ci0*8]);                         \
    GLDS(vg1 + (sbase),            &smem[b][1][ci1*8]);                         \
  } while (0)

  // hoisted LDS fragment pointers (buf 0 bases; buf 1 = +8192 u16, folds to imm)
  const int fl = FSW(l31);
  const u16* kP0 = &smem[0][0][(sh*32 + l31)*64 + (((0+hi) ^ fl) * 8)];
  const u16* kP1 = &smem[0][0][(sh*32 + l31)*64 + (((2+hi) ^ fl) * 8)];
  const u16* kP2 = &smem[0][0][(sh*32 + l31)*64 + (((4+hi) ^ fl) * 8)];
  const u16* kP3 = &smem[0][0][(sh*32 + l31)*64 + (((6+hi) ^ fl) * 8)];
  const u16* vP00 = &smem[0][1][l31*64      + (((sh*4 + 0 + hi) ^ fl) * 8)];
  const u16* vP01 = &smem[0][1][l31*64      + (((sh*4 + 2 + hi) ^ fl) * 8)];
  const u16* vP10 = &smem[0][1][(32+l31)*64 + (((sh*4 + 0 + hi) ^ fl) * 8)];
  const u16* vP11 = &smem[0][1][(32+l31)*64 + (((sh*4 + 2 + hi) ^ fl) * 8)];

  // acc[cb]: D-partial[c=cb*32+crow(r,hi)][t=t0+th*32+l31], s in sh-half
  // lacc: l-partial (all 16 entries identical = sum_s P over sh-half)
  f32x16 acc0 = {}, acc1 = {}, lacc = {};

  STAGE(0, 0);
  __syncthreads();

  // one tile: B = compile-time buf (0/1); reads use offset:B*16384 immediates
#define TILEBODY(B, DO_STAGE, SNEXT) do {                                       \
    if (DO_STAGE) STAGE(B ^ 1, SNEXT);                                          \
    f32x16 S0 = __builtin_amdgcn_mfma_f32_32x32x16_bf16(                        \
        *(const bf16x8*)(kP0 + (B)*8192), bq[0], fzero, 0, 0, 0);               \
    __builtin_amdgcn_s_setprio(1);                                              \
    S0 = __builtin_amdgcn_mfma_f32_32x32x16_bf16(                               \
        *(const bf16x8*)(kP1 + (B)*8192), bq[1], S0, 0, 0, 0);                  \
    S0 = __builtin_amdgcn_mfma_f32_32x32x16_bf16(                               \
        *(const bf16x8*)(kP2 + (B)*8192), bq[2], S0, 0, 0, 0);                  \
    S0 = __builtin_amdgcn_mfma_f32_32x32x16_bf16(                               \
        *(const bf16x8*)(kP3 + (B)*8192), bq[3], S0, 0, 0, 0);                  \
    __builtin_amdgcn_s_setprio(0);                                              \
    float p0[16];                                                               \
    _Pragma("unroll")                                                           \
    for (int i = 0; i < 16; ++i) p0[i] = __builtin_amdgcn_exp2f(S0[i]);         \
    uint d0[8];                                                                 \
    _Pragma("unroll")                                                           \
    for (int q = 0; q < 4; ++q) {                                               \
      asm("v_cvt_pk_bf16_f32 %0, %1, %2" : "=v"(d0[2*q+0]) : "v"(p0[4*q+0]), "v"(p0[4*q+1])); \
      asm("v_cvt_pk_bf16_f32 %0, %1, %2" : "=v"(d0[2*q+1]) : "v"(p0[4*q+2]), "v"(p0[4*q+3])); \
    }                                                                           \
    bf16x8 pf0, pf1;                                                            \
    {                                                                           \
      uint X0 = d0[0], X1 = d0[1], Y0 = d0[2], Y1 = d0[3];                      \
      asm("v_permlane32_swap_b32 %0, %1" : "+v"(X0), "+v"(Y0));                 \
      asm("v_permlane32_swap_b32 %0, %1" : "+v"(X1), "+v"(Y1));                 \
      uint4 u = {X0, X1, Y0, Y1};                                               \
      pf0 = __builtin_bit_cast(bf16x8, u);                                      \
    }                                                                           \
    {                                                                           \
      uint X0 = d0[4], X1 = d0[5], Y0 = d0[6], Y1 = d0[7];                      \
      asm("v_permlane32_swap_b32 %0, %1" : "+v"(X0), "+v"(Y0));                 \
      asm("v_permlane32_swap_b32 %0, %1" : "+v"(X1), "+v"(Y1));                 \
      uint4 u = {X0, X1, Y0, Y1};                                               \
      pf1 = __builtin_bit_cast(bf16x8, u);                                      \
    }                                                                           \
    __builtin_amdgcn_s_setprio(1);                                              \
    acc0 = __builtin_amdgcn_mfma_f32_32x32x16_bf16(                             \
        *(const bf16x8*)(vP00 + (B)*8192), pf0, acc0, 0, 0, 0);                 \
    acc1 = __builtin_amdgcn_mfma_f32_32x32x16_bf16(                             \
        *(const bf16x8*)(vP10 + (B)*8192), pf0, acc1, 0, 0, 0);                 \
    lacc = __builtin_amdgcn_mfma_f32_32x32x16_bf16(aone, pf0, lacc, 0, 0, 0);   \
    acc0 = __builtin_amdgcn_mfma_f32_32x32x16_bf16(                             \
        *(const bf16x8*)(vP01 + (B)*8192), pf1, acc0, 0, 0, 0);                 \
    acc1 = __builtin_amdgcn_mfma_f32_32x32x16_bf16(                             \
        *(const bf16x8*)(vP11 + (B)*8192), pf1, acc1, 0, 0, 0);                 \
    lacc = __builtin_amdgcn_mfma_f32_32x32x16_bf16(aone, pf1, lacc, 0, 0, 0);   \
    __builtin_amdgcn_s_setprio(0);                                              \
    __syncthreads();                                                            \
  } while (0)

  // main: unrolled x2 so buf is compile-time (SEQ/128 = 16 iterations)
  for (int s0 = 0; s0 < SEQ; s0 += 128) {
    TILEBODY(0, true, s0 + 64);                     // tile s0 (buf0), stage s0+64
    TILEBODY(1, s0 + 128 < SEQ, s0 + 128);          // tile s0+64 (buf1), stage s0+128
  }
#undef TILEBODY
#undef STAGE
#undef GLDS

  // epilogue: reduce partials across sh via LDS (r14-validated layout).
  // [frag][r][lane]: bank = lane%32, 2-way (free). frag = th*2 + cb.
  // l: lacc[0] (all entries equal; k-dim already summed both hi halves).
  float* ep = (float*)&smem[0][0][0];
  float* lp = ep + 4*1024;
  if (sh == 1) {
    float* b0 = ep + (th*2+0)*1024 + lane;
    float* b1 = ep + (th*2+1)*1024 + lane;
#pragma unroll
    for (int r = 0; r < 16; ++r) { b0[r*64] = acc0[r]; b1[r*64] = acc1[r]; }
    lp[th*64 + lane] = lacc[0];
  }
  __syncthreads();
  if (sh == 0) {
    const float* b0 = ep + (th*2+0)*1024 + lane;
    const float* b1 = ep + (th*2+1)*1024 + lane;
#pragma unroll
    for (int r = 0; r < 16; ++r) { acc0[r] += b0[r*64]; acc1[r] += b1[r*64]; }
    float lt = lacc[0] + lp[th*64 + lane];
    float linv = 1.0f / lt;
    float* ob = out + (size_t)(bh*64) * SEQ + t0 + th*32 + l31;
#pragma unroll
    for (int r = 0; r < 16; ++r) {
      int c0 = (r & 3) + 8*(r >> 2) + 4*hi;
      ob[(size_t)c0 * SEQ]        = acc0[r] * linv;
      ob[(size_t)(32 + c0) * SEQ] = acc1[r] * linv;
    }
  }
}

extern "C" void kernel_launch(void* const* d_in, const int* in_sizes, int n_in,
                              void* d_out, int out_size, void* d_ws, size_t ws_size,
                              hipStream_t stream) {
  const float* qkv = (const float*)d_in[0];
  float* out = (float*)d_out;
  u16* qT = (u16*)d_ws;
  u16* kT = qT + (size_t)32*SEQ*DH;
  u16* vB = kT + (size_t)32*SEQ*DH;
  prepass<<<4096, 256, 0, stream>>>(qkv, qT, kT, vB);
  attn<<<1024, 256, 0, stream>>>(qT, kT, vB, out);
}

// Round 21
// 61.695 us; speedup vs baseline: 1.1300x; 1.0147x over previous
//
#include <hip/hip_runtime.h>
#include <hip/hip_bf16.h>

typedef unsigned short u16;
typedef unsigned int uint;
typedef __bf16 bf16x8 __attribute__((ext_vector_type(8)));
typedef float f32x16 __attribute__((ext_vector_type(16)));

#define SEQ 2048
#define DH  64
// ws: kT [32][2048][64] bf16 | v [32][64][2048] bf16  (Q handled inside attn)

__device__ __forceinline__ u16 f2bf(float x) {
  __bf16 h = (__bf16)x;
  return __builtin_bit_cast(u16, h);
}

// LDS chunk swizzle (16B chunks, 8 per 64-elem row): slot = ch ^ FSW(row).
// Uses row bits 0-2 only -> invariant under +8/+32 row offsets.
#define FSW(r) ((((r) & 3) << 1) | (((r) >> 2) & 1))

// ---- pre-pass (single launch, 3072 blocks): K transpose + V convert ----
// Q dropped (each attn block stages its own disjoint Q tile -> saves 24MB
// of HBM round-trip; pre-pass was at its roofline for the old 72MB).
__global__ __launch_bounds__(256) void prepass(const float* __restrict__ qkv,
                                               u16* __restrict__ kT,
                                               u16* __restrict__ vB) {
  int idx = blockIdx.x;
  __shared__ float tile[64][65];
  if (idx < 1024) {
    // transpose k: idx = bh(32) x ttile(32)
    int bh = idx >> 5;
    int t0 = (idx & 31) * 64;
    int b = bh >> 3, h = bh & 7;
    const float* src = qkv + ((size_t)(b*1536 + 512 + h*64)) * SEQ;
    u16* dst = kT + (size_t)bh * SEQ * DH;

    int tl = threadIdx.x & 63;
    int cw = threadIdx.x >> 6;
#pragma unroll
    for (int i = 0; i < 16; ++i) {
      int c = cw + 4*i;
      tile[c][tl] = src[(size_t)c*SEQ + t0 + tl];
    }
    __syncthreads();
    int cl2 = (threadIdx.x & 31) * 2;
    int tw  = threadIdx.x >> 5;
#pragma unroll
    for (int i = 0; i < 8; ++i) {
      int t = tw + 8*i;
      unsigned int lo = f2bf(tile[cl2][t]);
      unsigned int hi = f2bf(tile[cl2+1][t]);
      *(unsigned int*)(dst + (size_t)(t0 + t)*DH + cl2) = lo | (hi << 16);
    }
  } else {
    // convert v row: row = idx - 1024 = bh*64 + c
    int row = idx - 1024;
    int bh = row >> 6, c = row & 63;
    int b = bh >> 3, h = bh & 7;
    const float4* src = (const float4*)(qkv + ((size_t)(b*1536 + 1024 + h*64 + c)) * SEQ);
    u16* dst = vB + (size_t)row * SEQ;
    int tid = threadIdx.x;
    float4 a = src[tid*2];
    float4 bq = src[tid*2+1];
    union { u16 u[8]; int4 v4; } pk;
    pk.u[0]=f2bf(a.x); pk.u[1]=f2bf(a.y); pk.u[2]=f2bf(a.z); pk.u[3]=f2bf(a.w);
    pk.u[4]=f2bf(bq.x); pk.u[5]=f2bf(bq.y); pk.u[6]=f2bf(bq.z); pk.u[7]=f2bf(bq.w);
    *(int4*)(dst + tid*8) = pk.v4;
  }
}

// ---- flash attention: r20 loop/epilogue verbatim + in-prologue Q staging ----
// Q tile (64 fp32 rows x 64 t) staged into padded LDS, scale folded; frags
// read at stride-65 (pad -> conflict-light), packed with the validated
// cvt_pk convention (first operand -> low half). One-time cost ~1-2k cy.
// Carried validated: l-via-MFMA, fixed-m softmax, VALU trim (hoisted ptrs,
// compile-time buf via x2 unroll, fzero C), 1024 blocks x 4 waves
// (th 32 t-cols, sh s-half), BK=64, 32KB dbuf LDS, 4 blocks/CU.
__global__ __launch_bounds__(256, 4) void attn(const float* __restrict__ qkv,
                                               const u16* __restrict__ kT,
                                               const u16* __restrict__ vB,
                                               float* __restrict__ out) {
  // XCD-bijective swizzle (1024 blocks): 128 consecutive per XCD -> 4 heads/XCD
  const int lb = (blockIdx.x & 7) * 128 + (blockIdx.x >> 3);
  const int bh = lb >> 5;           // 32 t-tiles (of 64) per head
  const int t0 = (lb & 31) * 64;
  const int tid  = threadIdx.x;
  const int wave = tid >> 6;        // 0..3
  const int th   = wave & 1;        // t-half: cols t0 + th*32 + l31
  const int sh   = wave >> 1;       // s-half: rows sh*32 + l31 of each 64-tile
  const int lane = tid & 63;
  const int l31  = lane & 31;
  const int hi   = lane >> 5;

  // [buf][K=0/V=1][64 rows x 8 chunks of 16B] = 32KB
  __shared__ __align__(16) u16 smem[2][2][64*64];

  // ---- prologue: stage + transpose + scale Q from fp32 qkv (one-time) ----
  bf16x8 bq[4];
  {
    float* qtile = (float*)&smem[0][0][0];   // [64][65] fp32 = 16.6KB < 32KB
    const float* qsrc = qkv + ((size_t)((bh >> 3)*1536 + (bh & 7)*64)) * SEQ + t0;
    const float qscale = 0.1803368801111244f;   // 0.125 * log2(e)
    int qc = tid >> 2, tb = (tid & 3) * 16;
    const float4* s4 = (const float4*)(qsrc + (size_t)qc*SEQ + tb);
    float4 v0 = s4[0], v1 = s4[1], v2 = s4[2], v3 = s4[3];
    float* qd = qtile + qc*65 + tb;
    qd[0]=v0.x*qscale; qd[1]=v0.y*qscale; qd[2]=v0.z*qscale; qd[3]=v0.w*qscale;
    qd[4]=v1.x*qscale; qd[5]=v1.y*qscale; qd[6]=v1.z*qscale; qd[7]=v1.w*qscale;
    qd[8]=v2.x*qscale; qd[9]=v2.y*qscale; qd[10]=v2.z*qscale; qd[11]=v2.w*qscale;
    qd[12]=v3.x*qscale; qd[13]=v3.y*qscale; qd[14]=v3.z*qscale; qd[15]=v3.w*qscale;
    __syncthreads();
    int tloc = th*32 + l31;
#pragma unroll
    for (int kb = 0; kb < 4; ++kb) {
      uint dd[4];
#pragma unroll
      for (int e = 0; e < 4; ++e) {
        float lo = qtile[(kb*16 + hi*8 + 2*e    )*65 + tloc];
        float hh = qtile[(kb*16 + hi*8 + 2*e + 1)*65 + tloc];
        asm("v_cvt_pk_bf16_f32 %0, %1, %2" : "=v"(dd[e]) : "v"(lo), "v"(hh));
      }
      uint4 u = {dd[0], dd[1], dd[2], dd[3]};
      bq[kb] = __builtin_bit_cast(bf16x8, u);
    }
    __syncthreads();   // all reads done before K/V staging overwrites smem
  }

  // ones A-fragment (bf16 1.0 = 0x3F80) for the l-MFMA; persistent zero C
  const uint4 uones = {0x3F803F80u, 0x3F803F80u, 0x3F803F80u, 0x3F803F80u};
  const bf16x8 aone = __builtin_bit_cast(bf16x8, uones);
  const f32x16 fzero = {};

  // staging: per thread 2 K-chunks + 2 V-chunks per 64-tile, pre-swizzled src
  const u16* ksrc0 = kT + (size_t)bh*SEQ*DH;
  const u16* vsrc0 = vB + (size_t)bh*DH*SEQ;
  const int ci0 = (wave*2+0)*64 + lane;   // chunk 0..511
  const int ci1 = (wave*2+1)*64 + lane;
  const int kr0 = ci0 >> 3, kc0 = ci0 & 7;
  const int kr1 = ci1 >> 3, kc1 = ci1 & 7;
  const u16* kg0 = ksrc0 + (size_t)kr0*DH + ((kc0 ^ FSW(kr0)) * 8);
  const u16* kg1 = ksrc0 + (size_t)kr1*DH + ((kc1 ^ FSW(kr1)) * 8);
  const u16* vg0 = vsrc0 + (size_t)kr0*SEQ + ((kc0 ^ FSW(kr0)) * 8);
  const u16* vg1 = vsrc0 + (size_t)kr1*SEQ + ((kc1 ^ FSW(kr1)) * 8);

#define GLDS(src, dst) __builtin_amdgcn_global_load_lds(                        \
    (const __attribute__((address_space(1))) unsigned int*)(src),               \
    (__attribute__((address_space(3))) unsigned int*)(dst), 16, 0, 0)
#define STAGE(b, sbase) do {                                                    \
    GLDS(kg0 + (size_t)(sbase)*DH, &smem[b][0][ci0*8]);                         \
    GLDS(kg1 + (size_t)(sbase)*DH, &smem[b][0][ci1*8]);                         \
    GLDS(vg0 + (sbase),            &smem[b][1][ci0*8]);                         \
    GLDS(vg1 + (sbase),            &smem[b][1][ci1*8]);                         \
  } while (0)

  // hoisted LDS fragment pointers (buf 0 bases; buf 1 = +8192 u16 -> imm)
  const int fl = FSW(l31);
  const u16* kP0 = &smem[0][0][(sh*32 + l31)*64 + (((0+hi) ^ fl) * 8)];
  const u16* kP1 = &smem[0][0][(sh*32 + l31)*64 + (((2+hi) ^ fl) * 8)];
  const u16* kP2 = &smem[0][0][(sh*32 + l31)*64 + (((4+hi) ^ fl) * 8)];
  const u16* kP3 = &smem[0][0][(sh*32 + l31)*64 + (((6+hi) ^ fl) * 8)];
  const u16* vP00 = &smem[0][1][l31*64      + (((sh*4 + 0 + hi) ^ fl) * 8)];
  const u16* vP01 = &smem[0][1][l31*64      + (((sh*4 + 2 + hi) ^ fl) * 8)];
  const u16* vP10 = &smem[0][1][(32+l31)*64 + (((sh*4 + 0 + hi) ^ fl) * 8)];
  const u16* vP11 = &smem[0][1][(32+l31)*64 + (((sh*4 + 2 + hi) ^ fl) * 8)];

  // acc[cb]: D-partial[c=cb*32+crow(r,hi)][t=t0+th*32+l31], s in sh-half
  // lacc: l-partial (all 16 entries identical = sum_s P over sh-half)
  f32x16 acc0 = {}, acc1 = {}, lacc = {};

  STAGE(0, 0);
  __syncthreads();

  // one tile: B = compile-time buf (0/1); reads use offset:B*16384 immediates
#define TILEBODY(B, DO_STAGE, SNEXT) do {                                       \
    if (DO_STAGE) STAGE(B ^ 1, SNEXT);                                          \
    f32x16 S0 = __builtin_amdgcn_mfma_f32_32x32x16_bf16(                        \
        *(const bf16x8*)(kP0 + (B)*8192), bq[0], fzero, 0, 0, 0);               \
    __builtin_amdgcn_s_setprio(1);                                              \
    S0 = __builtin_amdgcn_mfma_f32_32x32x16_bf16(                               \
        *(const bf16x8*)(kP1 + (B)*8192), bq[1], S0, 0, 0, 0);                  \
    S0 = __builtin_amdgcn_mfma_f32_32x32x16_bf16(                               \
        *(const bf16x8*)(kP2 + (B)*8192), bq[2], S0, 0, 0, 0);                  \
    S0 = __builtin_amdgcn_mfma_f32_32x32x16_bf16(                               \
        *(const bf16x8*)(kP3 + (B)*8192), bq[3], S0, 0, 0, 0);                  \
    __builtin_amdgcn_s_setprio(0);                                              \
    float p0[16];                                                               \
    _Pragma("unroll")                                                           \
    for (int i = 0; i < 16; ++i) p0[i] = __builtin_amdgcn_exp2f(S0[i]);         \
    uint d0[8];                                                                 \
    _Pragma("unroll")                                                           \
    for (int q = 0; q < 4; ++q) {                                               \
      asm("v_cvt_pk_bf16_f32 %0, %1, %2" : "=v"(d0[2*q+0]) : "v"(p0[4*q+0]), "v"(p0[4*q+1])); \
      asm("v_cvt_pk_bf16_f32 %0, %1, %2" : "=v"(d0[2*q+1]) : "v"(p0[4*q+2]), "v"(p0[4*q+3])); \
    }                                                                           \
    bf16x8 pf0, pf1;                                                            \
    {                                                                           \
      uint X0 = d0[0], X1 = d0[1], Y0 = d0[2], Y1 = d0[3];                      \
      asm("v_permlane32_swap_b32 %0, %1" : "+v"(X0), "+v"(Y0));                 \
      asm("v_permlane32_swap_b32 %0, %1" : "+v"(X1), "+v"(Y1));                 \
      uint4 u = {X0, X1, Y0, Y1};                                               \
      pf0 = __builtin_bit_cast(bf16x8, u);                                      \
    }                                                                           \
    {                                                                           \
      uint X0 = d0[4], X1 = d0[5], Y0 = d0[6], Y1 = d0[7];                      \
      asm("v_permlane32_swap_b32 %0, %1" : "+v"(X0), "+v"(Y0));                 \
      asm("v_permlane32_swap_b32 %0, %1" : "+v"(X1), "+v"(Y1));                 \
      uint4 u = {X0, X1, Y0, Y1};                                               \
      pf1 = __builtin_bit_cast(bf16x8, u);                                      \
    }                                                                           \
    __builtin_amdgcn_s_setprio(1);                                              \
    acc0 = __builtin_amdgcn_mfma_f32_32x32x16_bf16(                             \
        *(const bf16x8*)(vP00 + (B)*8192), pf0, acc0, 0, 0, 0);                 \
    acc1 = __builtin_amdgcn_mfma_f32_32x32x16_bf16(                             \
        *(const bf16x8*)(vP10 + (B)*8192), pf0, acc1, 0, 0, 0);                 \
    lacc = __builtin_amdgcn_mfma_f32_32x32x16_bf16(aone, pf0, lacc, 0, 0, 0);   \
    acc0 = __builtin_amdgcn_mfma_f32_32x32x16_bf16(                             \
        *(const bf16x8*)(vP01 + (B)*8192), pf1, acc0, 0, 0, 0);                 \
    acc1 = __builtin_amdgcn_mfma_f32_32x32x16_bf16(                             \
        *(const bf16x8*)(vP11 + (B)*8192), pf1, acc1, 0, 0, 0);                 \
    lacc = __builtin_amdgcn_mfma_f32_32x32x16_bf16(aone, pf1, lacc, 0, 0, 0);   \
    __builtin_amdgcn_s_setprio(0);                                              \
    __syncthreads();                                                            \
  } while (0)

  // main: unrolled x2 so buf is compile-time (SEQ/128 = 16 iterations)
  for (int s0 = 0; s0 < SEQ; s0 += 128) {
    TILEBODY(0, true, s0 + 64);                     // tile s0 (buf0), stage s0+64
    TILEBODY(1, s0 + 128 < SEQ, s0 + 128);          // tile s0+64 (buf1), stage s0+128
  }
#undef TILEBODY
#undef STAGE
#undef GLDS

  // epilogue: reduce partials across sh via LDS (r14-validated layout).
  // [frag][r][lane]: bank = lane%32, 2-way (free). frag = th*2 + cb.
  // l: lacc[0] (all entries equal; k-dim already summed both hi halves).
  float* ep = (float*)&smem[0][0][0];
  float* lp = ep + 4*1024;
  if (sh == 1) {
    float* b0 = ep + (th*2+0)*1024 + lane;
    float* b1 = ep + (th*2+1)*1024 + lane;
#pragma unroll
    for (int r = 0; r < 16; ++r) { b0[r*64] = acc0[r]; b1[r*64] = acc1[r]; }
    lp[th*64 + lane] = lacc[0];
  }
  __syncthreads();
  if (sh == 0) {
    const float* b0 = ep + (th*2+0)*1024 + lane;
    const float* b1 = ep + (th*2+1)*1024 + lane;
#pragma unroll
    for (int r = 0; r < 16; ++r) { acc0[r] += b0[r*64]; acc1[r] += b1[r*64]; }
    float lt = lacc[0] + lp[th*64 + lane];
    float linv = 1.0f / lt;
    float* ob = out + (size_t)(bh*64) * SEQ + t0 + th*32 + l31;
#pragma unroll
    for (int r = 0; r < 16; ++r) {
      int c0 = (r & 3) + 8*(r >> 2) + 4*hi;
      ob[(size_t)c0 * SEQ]        = acc0[r] * linv;
      ob[(size_t)(32 + c0) * SEQ] = acc1[r] * linv;
    }
  }
}

extern "C" void kernel_launch(void* const* d_in, const int* in_sizes, int n_in,
                              void* d_out, int out_size, void* d_ws, size_t ws_size,
                              hipStream_t stream) {
  const float* qkv = (const float*)d_in[0];
  float* out = (float*)d_out;
  u16* kT = (u16*)d_ws;
  u16* vB = kT + (size_t)32*SEQ*DH;
  prepass<<<3072, 256, 0, stream>>>(qkv, kT, vB);
  attn<<<1024, 256, 0, stream>>>(qkv, kT, vB, out);
}